// Round 1
// baseline (228.786 us; speedup 1.0000x reference)
//
#include <hip/hip_runtime.h>
#include <math.h>

#define THREADS 256
#define PPB 256  // pairs per block

// Compute one Rodrigues rotation matrix from raw vec1/vec2 components,
// mirroring the JAX reference's branch semantics exactly.
__device__ __forceinline__ void compute_R(float v1x, float v1y, float v1z,
                                          float v2x, float v2y, float v2z,
                                          float R[9]) {
    // normalize a, b
    float na = sqrtf(v1x*v1x + v1y*v1y + v1z*v1z);
    float nb = sqrtf(v2x*v2x + v2y*v2y + v2z*v2z);
    float ia = 1.0f / na;
    float ib = 1.0f / nb;
    float ax = v1x*ia, ay = v1y*ia, az = v1z*ia;
    float bx = v2x*ib, by = v2y*ib, bz = v2z*ib;

    // v = a x b ; c = a.b ; s2 = |v|^2
    float vx = ay*bz - az*by;
    float vy = az*bx - ax*bz;
    float vz = ax*by - ay*bx;
    float c  = ax*bx + ay*by + az*bz;
    float s2 = vx*vx + vy*vy + vz*vz;
    float s  = sqrtf(s2);

    float s2_safe = (s2 > 0.0f) ? s2 : 1.0f;
    float coef = (1.0f - c) / s2_safe;

    // K = [[0,-vz,vy],[vz,0,-vx],[-vy,vx,0]] ; K@K = v v^T - s2 I
    float kxx = -(vz*vz + vy*vy);
    float kyy = -(vx*vx + vz*vz);
    float kzz = -(vx*vx + vy*vy);
    float kxy = vx*vy, kxz = vx*vz, kyz = vy*vz;

    R[0] = 1.0f       + coef*kxx;
    R[1] =      -vz   + coef*kxy;
    R[2] =       vy   + coef*kxz;
    R[3] =       vz   + coef*kxy;
    R[4] = 1.0f       + coef*kyy;
    R[5] =      -vx   + coef*kyz;
    R[6] =      -vy   + coef*kxz;
    R[7] =       vx   + coef*kyz;
    R[8] = 1.0f       + coef*kzz;

    // Degenerate branches (s < 1e-30): essentially never taken for random
    // normal inputs, but must match reference semantics.
    if (s < 1e-30f) {
        if (c > 0.0f) {
            R[0] = 1.0f; R[1] = 0.0f; R[2] = 0.0f;
            R[3] = 0.0f; R[4] = 1.0f; R[5] = 0.0f;
            R[6] = 0.0f; R[7] = 0.0f; R[8] = 1.0f;
        } else if (c < 0.0f) {
            // antipodal: axis = close_e1 ? e2 : e1 ; perp = normalize(a x axis)
            bool close_e1 = (fabsf(ax - 1.0f) <= (1e-8f + 1e-5f)) &&
                            (fabsf(ay)        <=  1e-8f)          &&
                            (fabsf(az)        <=  1e-8f);
            float px, py, pz;
            if (close_e1) {        // a x e2 = (-az, 0, ax)
                px = -az; py = 0.0f; pz = ax;
            } else {               // a x e1 = (0, az, -ay)
                px = 0.0f; py = az; pz = -ay;
            }
            float pn = sqrtf(px*px + py*py + pz*pz);
            float ip = (pn > 0.0f) ? (1.0f/pn) : 1.0f;
            px *= ip; py *= ip; pz *= ip;
            float pp = px*px + py*py + pz*pz;  // ~1, kept explicit like ref
            // R180 = I + 2*(p p^T - pp*I)
            R[0] = 1.0f + 2.0f*(px*px - pp);
            R[1] =        2.0f*(px*py);
            R[2] =        2.0f*(px*pz);
            R[3] =        2.0f*(px*py);
            R[4] = 1.0f + 2.0f*(py*py - pp);
            R[5] =        2.0f*(py*pz);
            R[6] =        2.0f*(px*pz);
            R[7] =        2.0f*(py*pz);
            R[8] = 1.0f + 2.0f*(pz*pz - pp);
        }
        // c == 0 exactly with s == 0: keep Rodrigues result (matches ref)
    }
}

// Main kernel: 256 pairs / block. Inputs staged through LDS via coalesced
// float4 loads; outputs staged through LDS and written as coalesced float4.
// LDS strides 3 and 9 floats are odd -> conflict-free on 32 banks (the
// residual 2-way wave64 aliasing is free on gfx950).
__global__ __launch_bounds__(THREADS) void rot_main_kernel(
        const float* __restrict__ v1, const float* __restrict__ v2,
        float* __restrict__ out) {
    __shared__ float s_in1[PPB * 3];
    __shared__ float s_in2[PPB * 3];
    __shared__ float s_out[PPB * 9];

    const int tid = threadIdx.x;
    const long long blk = blockIdx.x;

    // stage inputs: PPB*3/4 = 192 float4 per input
    const float4* v1f4 = (const float4*)v1 + blk * (PPB * 3 / 4);
    const float4* v2f4 = (const float4*)v2 + blk * (PPB * 3 / 4);
    if (tid < PPB * 3 / 4) {
        ((float4*)s_in1)[tid] = v1f4[tid];
        ((float4*)s_in2)[tid] = v2f4[tid];
    }
    __syncthreads();

    float R[9];
    compute_R(s_in1[tid*3+0], s_in1[tid*3+1], s_in1[tid*3+2],
              s_in2[tid*3+0], s_in2[tid*3+1], s_in2[tid*3+2], R);

    #pragma unroll
    for (int k = 0; k < 9; ++k) s_out[tid*9 + k] = R[k];
    __syncthreads();

    // coalesced output: PPB*9/4 = 576 float4 per block
    float4* of4 = (float4*)out + blk * (PPB * 9 / 4);
    const float4* so4 = (const float4*)s_out;
    #pragma unroll
    for (int base = 0; base < PPB * 9 / 4; base += THREADS) {
        int idx = base + tid;
        if (idx < PPB * 9 / 4) of4[idx] = so4[idx];
    }
}

// Tail kernel for pair counts not divisible by PPB (not used at B*NB=4M,
// but keeps the kernel shape-robust). Scalar loads/stores.
__global__ __launch_bounds__(THREADS) void rot_tail_kernel(
        const float* __restrict__ v1, const float* __restrict__ v2,
        float* __restrict__ out, long long base_pair, long long n_pairs) {
    long long p = base_pair + (long long)blockIdx.x * THREADS + threadIdx.x;
    if (p >= n_pairs) return;
    float R[9];
    compute_R(v1[p*3+0], v1[p*3+1], v1[p*3+2],
              v2[p*3+0], v2[p*3+1], v2[p*3+2], R);
    #pragma unroll
    for (int k = 0; k < 9; ++k) out[p*9 + k] = R[k];
}

extern "C" void kernel_launch(void* const* d_in, const int* in_sizes, int n_in,
                              void* d_out, int out_size, void* d_ws, size_t ws_size,
                              hipStream_t stream) {
    (void)n_in; (void)out_size; (void)d_ws; (void)ws_size;
    const float* v1 = (const float*)d_in[0];
    const float* v2 = (const float*)d_in[1];
    float* out = (float*)d_out;

    long long n_pairs = (long long)in_sizes[0] / 3;
    long long full_blocks = n_pairs / PPB;
    if (full_blocks > 0) {
        rot_main_kernel<<<(int)full_blocks, THREADS, 0, stream>>>(v1, v2, out);
    }
    long long rem = n_pairs - full_blocks * PPB;
    if (rem > 0) {
        rot_tail_kernel<<<(int)((rem + THREADS - 1) / THREADS), THREADS, 0, stream>>>(
            v1, v2, out, full_blocks * PPB, n_pairs);
    }
}

// Round 4
// 224.066 us; speedup vs baseline: 1.0211x; 1.0211x over previous
//
#include <hip/hip_runtime.h>
#include <math.h>

#define THREADS 256
#define PPB 256  // pairs per block

// Native 4-float vector (works with __builtin_nontemporal_store, unlike HIP's
// class-based float4).
typedef float f4 __attribute__((ext_vector_type(4)));

// Fast hw approximations: v_rsq_f32 / v_rcp_f32 (~1 ulp; validation threshold
// is 2e-2 absmax and the exact-IEEE version measured 3.9e-3, so these are free).
__device__ __forceinline__ float frsq(float x) { return __builtin_amdgcn_rsqf(x); }
__device__ __forceinline__ float frcp(float x) { return __builtin_amdgcn_rcpf(x); }

// One Rodrigues rotation matrix, mirroring the JAX reference branch semantics.
// Note: s < 1e-30 (with s = sqrt(s2)) is equivalent to s2 == 0 in fp32, since
// the smallest positive s2 (denormal ~1.4e-45) gives s ~ 3.7e-23 >> 1e-30.
__device__ __forceinline__ void compute_R(float v1x, float v1y, float v1z,
                                          float v2x, float v2y, float v2z,
                                          float R[9]) {
    float d1 = v1x*v1x + v1y*v1y + v1z*v1z;
    float d2 = v2x*v2x + v2y*v2y + v2z*v2z;
    float ia = frsq(d1);
    float ib = frsq(d2);
    float ax = v1x*ia, ay = v1y*ia, az = v1z*ia;
    float bx = v2x*ib, by = v2y*ib, bz = v2z*ib;

    // v = a x b ; c = a.b ; s2 = |v|^2
    float vx = ay*bz - az*by;
    float vy = az*bx - ax*bz;
    float vz = ax*by - ay*bx;
    float c  = ax*bx + ay*by + az*bz;
    float s2 = vx*vx + vy*vy + vz*vz;

    float coef = (1.0f - c) * ((s2 > 0.0f) ? frcp(s2) : 1.0f);

    // K@K = v v^T - s2 I
    float kxx = -(vz*vz + vy*vy);
    float kyy = -(vx*vx + vz*vz);
    float kzz = -(vx*vx + vy*vy);
    float kxy = vx*vy, kxz = vx*vz, kyz = vy*vz;

    R[0] = 1.0f     + coef*kxx;
    R[1] =      -vz + coef*kxy;
    R[2] =       vy + coef*kxz;
    R[3] =       vz + coef*kxy;
    R[4] = 1.0f     + coef*kyy;
    R[5] =      -vx + coef*kyz;
    R[6] =      -vy + coef*kxz;
    R[7] =       vx + coef*kyz;
    R[8] = 1.0f     + coef*kzz;

    // Degenerate branches (s2 == 0): never taken for random normal inputs;
    // compiler emits s_cbranch_execz skip, so cost is ~2 cycles.
    if (s2 == 0.0f) {
        if (c > 0.0f) {
            R[0] = 1.0f; R[1] = 0.0f; R[2] = 0.0f;
            R[3] = 0.0f; R[4] = 1.0f; R[5] = 0.0f;
            R[6] = 0.0f; R[7] = 0.0f; R[8] = 1.0f;
        } else if (c < 0.0f) {
            bool close_e1 = (fabsf(ax - 1.0f) <= (1e-8f + 1e-5f)) &&
                            (fabsf(ay)        <=  1e-8f)          &&
                            (fabsf(az)        <=  1e-8f);
            float px, py, pz;
            if (close_e1) {        // a x e2 = (-az, 0, ax)
                px = -az; py = 0.0f; pz = ax;
            } else {               // a x e1 = (0, az, -ay)
                px = 0.0f; py = az; pz = -ay;
            }
            float p2 = px*px + py*py + pz*pz;
            float ip = (p2 > 0.0f) ? frsq(p2) : 1.0f;
            px *= ip; py *= ip; pz *= ip;
            float pp = px*px + py*py + pz*pz;  // ~1, kept explicit like ref
            R[0] = 1.0f + 2.0f*(px*px - pp);
            R[1] =        2.0f*(px*py);
            R[2] =        2.0f*(px*pz);
            R[3] =        2.0f*(px*py);
            R[4] = 1.0f + 2.0f*(py*py - pp);
            R[5] =        2.0f*(py*pz);
            R[6] =        2.0f*(px*pz);
            R[7] =        2.0f*(py*pz);
            R[8] = 1.0f + 2.0f*(pz*pz - pp);
        }
    }
}

// 256 pairs/block. Inputs staged via coalesced float4 loads -> LDS (stride-3
// float reads, gcd(3,32)=1 -> conflict-free); outputs staged through LDS and
// written as coalesced nontemporal float4 (write-once data, skip L2 pollution).
// All index math 32-bit: max byte offset = 151 MB < 2^31.
// NOTE: 576 f4/block is NOT a multiple of THREADS=256 -> the bounds guard in
// the copy loop is REQUIRED (dropping it in R2 caused OOB stores -> abort).
__global__ __launch_bounds__(THREADS) void rot_main_kernel(
        const float* __restrict__ v1, const float* __restrict__ v2,
        float* __restrict__ out) {
    __shared__ float s_in1[PPB * 3];
    __shared__ float s_in2[PPB * 3];
    __shared__ float s_out[PPB * 9];

    const int tid = threadIdx.x;
    const int blk = blockIdx.x;

    const f4* v1f4 = (const f4*)v1 + blk * (PPB * 3 / 4);
    const f4* v2f4 = (const f4*)v2 + blk * (PPB * 3 / 4);
    if (tid < PPB * 3 / 4) {
        ((f4*)s_in1)[tid] = v1f4[tid];
        ((f4*)s_in2)[tid] = v2f4[tid];
    }
    __syncthreads();

    float R[9];
    compute_R(s_in1[tid*3+0], s_in1[tid*3+1], s_in1[tid*3+2],
              s_in2[tid*3+0], s_in2[tid*3+1], s_in2[tid*3+2], R);

    #pragma unroll
    for (int k = 0; k < 9; ++k) s_out[tid*9 + k] = R[k];
    __syncthreads();

    f4* of4 = (f4*)out + blk * (PPB * 9 / 4);
    const f4* so4 = (const f4*)s_out;
    #pragma unroll
    for (int base = 0; base < PPB * 9 / 4; base += THREADS) {
        int idx = base + tid;
        if (idx < PPB * 9 / 4) {
            __builtin_nontemporal_store(so4[idx], &of4[idx]);
        }
    }
}

// Tail kernel for pair counts not divisible by PPB (unused at B*NB = 4M).
__global__ __launch_bounds__(THREADS) void rot_tail_kernel(
        const float* __restrict__ v1, const float* __restrict__ v2,
        float* __restrict__ out, long long base_pair, long long n_pairs) {
    long long p = base_pair + (long long)blockIdx.x * THREADS + threadIdx.x;
    if (p >= n_pairs) return;
    float R[9];
    compute_R(v1[p*3+0], v1[p*3+1], v1[p*3+2],
              v2[p*3+0], v2[p*3+1], v2[p*3+2], R);
    #pragma unroll
    for (int k = 0; k < 9; ++k) out[p*9 + k] = R[k];
}

extern "C" void kernel_launch(void* const* d_in, const int* in_sizes, int n_in,
                              void* d_out, int out_size, void* d_ws, size_t ws_size,
                              hipStream_t stream) {
    (void)n_in; (void)out_size; (void)d_ws; (void)ws_size;
    const float* v1 = (const float*)d_in[0];
    const float* v2 = (const float*)d_in[1];
    float* out = (float*)d_out;

    long long n_pairs = (long long)in_sizes[0] / 3;
    long long full_blocks = n_pairs / PPB;
    if (full_blocks > 0) {
        rot_main_kernel<<<(int)full_blocks, THREADS, 0, stream>>>(v1, v2, out);
    }
    long long rem = n_pairs - full_blocks * PPB;
    if (rem > 0) {
        rot_tail_kernel<<<(int)((rem + THREADS - 1) / THREADS), THREADS, 0, stream>>>(
            v1, v2, out, full_blocks * PPB, n_pairs);
    }
}